// Round 6
// baseline (375.422 us; speedup 1.0000x reference)
//
#include <hip/hip_runtime.h>
#include <hip/hip_bf16.h>

#define N_NODES  100000
#define N_EDGES  1600000
#define N_GRAPHS 256
#define F 64
#define NBUCK  782    // ceil(N_NODES/128), bucket = dst >> 7
#define CHUNK  4096   // edges per partition chunk
#define NCHUNK 391    // ceil(1.6M/4096)
#define GB     391    // ceil(N_NODES/256) gemm blocks (256 nodes/block)
#define NBIN   64     // node degree bins: bin = min(deg, 63)  (exact-degree binning)
#define NCHN   98     // ceil(N_NODES/1024) node chunks for bin counting sort

// ======== atomic-free CSR build: two-level counting sort ========

__global__ __launch_bounds__(1024) void k_hist(const int* __restrict__ dst, int* __restrict__ hist) {
    __shared__ int lh[NBUCK];
    int tid = threadIdx.x, chunk = blockIdx.x;
    for (int j = tid; j < NBUCK; j += 1024) lh[j] = 0;
    __syncthreads();
    int e0 = chunk * CHUNK;
#pragma unroll
    for (int i = 0; i < CHUNK / 1024; i++) {
        int e = e0 + i * 1024 + tid;
        if (e < N_EDGES) atomicAdd(&lh[dst[e] >> 7], 1);
    }
    __syncthreads();
    for (int j = tid; j < NBUCK; j += 1024) hist[chunk * NBUCK + j] = lh[j];
}

__global__ __launch_bounds__(512) void k_colscan(int* __restrict__ hist, int* __restrict__ btot) {
    __shared__ int ts[512];
    int b = blockIdx.x, tid = threadIdx.x;
    int v = (tid < NCHUNK) ? hist[tid * NBUCK + b] : 0;
    ts[tid] = v;
    __syncthreads();
    int x = v;
    for (int off = 1; off < 512; off <<= 1) {
        int t = (tid >= off) ? ts[tid - off] : 0;
        __syncthreads();
        x += t; ts[tid] = x;
        __syncthreads();
    }
    if (tid < NCHUNK) hist[tid * NBUCK + b] = x - v;
    if (tid == 511) btot[b] = x;
}

// block 0: scan bucket totals -> base; block 1: graph-boundary binary search
__global__ __launch_bounds__(512) void k_bscan_gstart(const int* __restrict__ btot, int* __restrict__ base,
                                                      const int* __restrict__ batch, int* __restrict__ gstart) {
    if (blockIdx.x == 1) {
        int g = threadIdx.x;
        if (g > N_GRAPHS) return;
        int lo = 0, hi = N_NODES;
        while (lo < hi) {
            int mid = (lo + hi) >> 1;
            if (batch[mid] < g) lo = mid + 1; else hi = mid;
        }
        gstart[g] = lo;
        return;
    }
    __shared__ int ts[256];
    int tid = threadIdx.x;
    int v[4], loc[4], run = 0;
    if (tid < 256) {
#pragma unroll
        for (int k = 0; k < 4; k++) {
            int c = tid * 4 + k;
            v[k] = (c < NBUCK) ? btot[c] : 0;
            loc[k] = run; run += v[k];
        }
        ts[tid] = run;
    }
    __syncthreads();
    int x = run;
    for (int off = 1; off < 256; off <<= 1) {
        int t = (tid >= off && tid < 256) ? ts[tid - off] : 0;
        __syncthreads();
        if (tid < 256) { x += t; ts[tid] = x; }
        __syncthreads();
    }
    if (tid < 256) {
        int texcl = x - run;
#pragma unroll
        for (int k = 0; k < 4; k++) {
            int c = tid * 4 + k;
            if (c < NBUCK) base[c] = texcl + loc[k];
        }
        if (tid == 255) base[NBUCK] = x;
    }
}

// edge partition (1024 threads, 3.1 KB LDS -> high occupancy)
__global__ __launch_bounds__(1024) void k_partition(const int* __restrict__ src, const int* __restrict__ dst,
                                                    const float* __restrict__ ew,
                                                    const int* __restrict__ hist, const int* __restrict__ base,
                                                    long long* __restrict__ part) {
    __shared__ int cursor[NBUCK];
    int tid = threadIdx.x, chunk = blockIdx.x;
    for (int j = tid; j < NBUCK; j += 1024) cursor[j] = base[j] + hist[chunk * NBUCK + j];
    __syncthreads();
    int e0 = chunk * CHUNK;
#pragma unroll
    for (int i = 0; i < CHUNK / 1024; i++) {
        int e = e0 + i * 1024 + tid;
        if (e < N_EDGES) {
            int d = dst[e];
            int pos = atomicAdd(&cursor[d >> 7], 1);
            unsigned lo = (unsigned)src[e] | ((unsigned)(d & 127) << 17);
            long long rec = (long long)((unsigned long long)lo |
                            ((unsigned long long)__float_as_uint(ew[e]) << 32));
            part[pos] = rec;
        }
    }
}

// ======== fused deg+scat (one launch; bucket's part slice stays L2-hot) ========
// Pass 1: degrees (LDS float atomics) -> dinv_g, counts -> row_off + LDS cursors.
// Pass 2: scatter esec = (src*128 byte-off, w).  Coef is the PLAIN edge weight:
// dinv[src] is folded into the H buffer by the GEMM epilogue (Hd = dinv*H), and
// dinv[dst] is applied once in agg. No dinv gather per edge anymore.
__global__ __launch_bounds__(512) void k_degscat(const long long* __restrict__ part,
                                                 const int* __restrict__ base,
                                                 float* __restrict__ dinv_g, int* __restrict__ row_off,
                                                 int2* __restrict__ esec) {
    __shared__ float fdeg[128];
    __shared__ int   cnt[128];
    __shared__ int   sc[128];
    __shared__ int   cursor[128];
    int b = blockIdx.x, tid = threadIdx.x;
    if (tid < 128) { fdeg[tid] = 1.0f; cnt[tid] = 0; }   // 1.0 = self-loop weight
    __syncthreads();
    int e0 = base[b], e1 = base[b + 1];
    for (int k = e0 + tid; k < e1; k += 512) {
        long long rec = part[k];
        int d7 = ((int)rec >> 17) & 127;
        atomicAdd(&fdeg[d7], __uint_as_float((unsigned)(rec >> 32)));
        atomicAdd(&cnt[d7], 1);
    }
    __syncthreads();
    int myc = 0, x = 0;
    if (tid < 128) {
        int node = b * 128 + tid;
        if (node < N_NODES) dinv_g[node] = rsqrtf(fdeg[tid]);
        myc = cnt[tid]; x = myc; sc[tid] = x;
    }
    __syncthreads();
    for (int off = 1; off < 128; off <<= 1) {
        int t = (tid < 128 && tid >= off) ? sc[tid - off] : 0;
        __syncthreads();
        if (tid < 128) { x += t; sc[tid] = x; }
        __syncthreads();
    }
    if (tid < 128) {
        int node = b * 128 + tid;
        int ro = e0 + (x - myc);
        if (node < N_NODES) row_off[node] = ro;
        cursor[tid] = ro;
    }
    if (b == 0 && tid == 0) row_off[N_NODES] = N_EDGES;
    __syncthreads();
    // pass 2: scatter (part slice is L2-hot from pass 1)
    for (int k = e0 + tid; k < e1; k += 512) {
        long long rec = part[k];
        int lo = (int)rec;
        int d7 = (lo >> 17) & 127;
        int s  = lo & 0x1FFFF;
        int pos = atomicAdd(&cursor[d7], 1);
        esec[pos] = make_int2(s << 7, (int)(unsigned)(rec >> 32));  // (byte off, raw w bits)
    }
    if (b == 0 && tid < 32) esec[N_EDGES + tid] = make_int2(0, 0);  // zero sentinels
}

// ======== node degree-binning: perm groups nodes with equal degree ========
// Waves take 8 consecutive perm entries -> the 8 per-lane serial streams have
// (almost always) equal trip counts -> near-zero slot waste in k_agg.

__global__ __launch_bounds__(1024) void k_nhist(const int* __restrict__ row_off, int* __restrict__ nhist) {
    __shared__ int lh[NBIN];
    int tid = threadIdx.x, c = blockIdx.x;
    if (tid < NBIN) lh[tid] = 0;
    __syncthreads();
    int n = c * 1024 + tid;
    if (n < N_NODES) {
        int len = row_off[n + 1] - row_off[n];
        int bin = len; if (bin > NBIN - 1) bin = NBIN - 1;
        atomicAdd(&lh[bin], 1);
    }
    __syncthreads();
    if (tid < NBIN) nhist[c * NBIN + tid] = lh[tid];
}

__global__ __launch_bounds__(1024) void k_nscan(int* __restrict__ nhist) {
    __shared__ int h[NCHN * NBIN];   // 98*64*4 = 25 KB
    __shared__ int tot[NBIN];
    int tid = threadIdx.x;
    for (int i = tid; i < NCHN * NBIN; i += 1024) h[i] = nhist[i];
    __syncthreads();
    if (tid < NBIN) {                       // exclusive scan over chunks, per bin
        int run = 0;
        for (int c = 0; c < NCHN; c++) { int v = h[c * NBIN + tid]; h[c * NBIN + tid] = run; run += v; }
        tot[tid] = run;
    }
    __syncthreads();
    if (tid == 0) {                         // exclusive scan over bins
        int run = 0;
        for (int b = 0; b < NBIN; b++) { int v = tot[b]; tot[b] = run; run += v; }
    }
    __syncthreads();
    for (int i = tid; i < NCHN * NBIN; i += 1024) nhist[i] = h[i] + tot[i & (NBIN - 1)];
}

__global__ __launch_bounds__(1024) void k_nscat(const int* __restrict__ row_off, const int* __restrict__ nhist,
                                                int* __restrict__ perm) {
    __shared__ int cur[NBIN];
    int tid = threadIdx.x, c = blockIdx.x;
    if (tid < NBIN) cur[tid] = nhist[c * NBIN + tid];
    __syncthreads();
    int n = c * 1024 + tid;
    if (n < N_NODES) {
        int len = row_off[n + 1] - row_off[n];
        int bin = len; if (bin > NBIN - 1) bin = NBIN - 1;
        int pos = atomicAdd(&cur[bin], 1);
        perm[pos] = n;
    }
}

// ---------------- GEMM1: Hd = dinv * (X_f32[N,128] @ W[128,64]), bf16 out ----------------
__global__ __launch_bounds__(256) void k_gemm1(const float* __restrict__ X,
                                               const float* __restrict__ W,
                                               const float* __restrict__ dinv,
                                               __hip_bfloat16* __restrict__ H) {
    constexpr int K = 128;
    constexpr int KC = 32;
    constexpr int XP = KC + 4;
    __shared__ float Xs[256 * XP];
    __shared__ float Ws[KC * F];
    const int tid  = threadIdx.x;
    const int fgrp = tid & 7;
    const int ngrp = tid >> 3;
    const int f0   = fgrp * 8;
    const int nb   = blockIdx.x * 256;

    float acc[8][8];
#pragma unroll
    for (int i = 0; i < 8; i++)
#pragma unroll
        for (int j = 0; j < 8; j++) acc[i][j] = 0.0f;

    for (int kc = 0; kc < K; kc += KC) {
        if (kc) __syncthreads();
#pragma unroll
        for (int pass = 0; pass < 8; pass++) {
            int idx = tid + pass * 256;
            int r = idx >> 3, q = idx & 7;
            int gr = nb + r; if (gr >= N_NODES) gr = N_NODES - 1;
            float4 v = *(const float4*)&X[(size_t)gr * K + kc + q * 4];
            *(float4*)&Xs[r * XP + q * 4] = v;
        }
#pragma unroll
        for (int pass = 0; pass < 2; pass++) {
            int idx = tid + pass * 256;
            float4 v = *(const float4*)&W[(size_t)(kc + (idx >> 4)) * F + (idx & 15) * 4];
            *(float4*)&Ws[idx * 4] = v;
        }
        __syncthreads();
#pragma unroll
        for (int k = 0; k < KC; k += 4) {
            float4 wa[4], wb[4];
#pragma unroll
            for (int kk = 0; kk < 4; kk++) {
                wa[kk] = *(const float4*)&Ws[(k + kk) * F + f0];
                wb[kk] = *(const float4*)&Ws[(k + kk) * F + f0 + 4];
            }
#pragma unroll
            for (int i = 0; i < 8; i++) {
                float4 xv = *(const float4*)&Xs[(ngrp + 32 * i) * XP + k];
#pragma unroll
                for (int kk = 0; kk < 4; kk++) {
                    float xk = (kk == 0) ? xv.x : (kk == 1) ? xv.y : (kk == 2) ? xv.z : xv.w;
                    acc[i][0] = fmaf(xk, wa[kk].x, acc[i][0]);
                    acc[i][1] = fmaf(xk, wa[kk].y, acc[i][1]);
                    acc[i][2] = fmaf(xk, wa[kk].z, acc[i][2]);
                    acc[i][3] = fmaf(xk, wa[kk].w, acc[i][3]);
                    acc[i][4] = fmaf(xk, wb[kk].x, acc[i][4]);
                    acc[i][5] = fmaf(xk, wb[kk].y, acc[i][5]);
                    acc[i][6] = fmaf(xk, wb[kk].z, acc[i][6]);
                    acc[i][7] = fmaf(xk, wb[kk].w, acc[i][7]);
                }
            }
        }
    }
#pragma unroll
    for (int i = 0; i < 8; i++) {
        int gn = nb + ngrp + 32 * i;
        if (gn < N_NODES) {
            float di = dinv[gn];
            __hip_bfloat16 hb[8];
#pragma unroll
            for (int j = 0; j < 8; j++) hb[j] = __float2bfloat16(acc[i][j] * di);
            *(uint4*)&H[(size_t)gn * F + f0] = *(uint4*)hb;
        }
    }
}

// ---------------- GEMM (layers 2/3): Hd = dinv * (X_bf16[N,64] @ W[64,64]), bf16 out ----------------
template <int K>
__global__ __launch_bounds__(256) void k_gemm(const unsigned short* __restrict__ X,
                                              const float* __restrict__ W,
                                              const float* __restrict__ dinv,
                                              __hip_bfloat16* __restrict__ H) {
    constexpr int KC = 32;
    constexpr int XP = KC + 4;
    __shared__ float Xs[256 * XP];
    __shared__ float Ws[KC * F];
    const int tid  = threadIdx.x;
    const int fgrp = tid & 7;
    const int ngrp = tid >> 3;
    const int f0   = fgrp * 8;
    const int nb   = blockIdx.x * 256;

    float acc[8][8];
#pragma unroll
    for (int i = 0; i < 8; i++)
#pragma unroll
        for (int j = 0; j < 8; j++) acc[i][j] = 0.0f;

    for (int kc = 0; kc < K; kc += KC) {
        if (kc) __syncthreads();
#pragma unroll
        for (int pass = 0; pass < 4; pass++) {
            int idx = tid + pass * 256;
            int r = idx >> 2, q = idx & 3;
            int gr = nb + r; if (gr >= N_NODES) gr = N_NODES - 1;
            uint4 v = *(const uint4*)&X[(size_t)gr * K + kc + q * 8];
            float* dp = &Xs[r * XP + q * 8];
            dp[0] = __uint_as_float(v.x << 16);
            dp[1] = __uint_as_float(v.x & 0xffff0000u);
            dp[2] = __uint_as_float(v.y << 16);
            dp[3] = __uint_as_float(v.y & 0xffff0000u);
            dp[4] = __uint_as_float(v.z << 16);
            dp[5] = __uint_as_float(v.z & 0xffff0000u);
            dp[6] = __uint_as_float(v.w << 16);
            dp[7] = __uint_as_float(v.w & 0xffff0000u);
        }
#pragma unroll
        for (int pass = 0; pass < 2; pass++) {
            int idx = tid + pass * 256;
            float4 v = *(const float4*)&W[(size_t)(kc + (idx >> 4)) * F + (idx & 15) * 4];
            *(float4*)&Ws[idx * 4] = v;
        }
        __syncthreads();
#pragma unroll
        for (int k = 0; k < KC; k += 4) {
            float4 wa[4], wb[4];
#pragma unroll
            for (int kk = 0; kk < 4; kk++) {
                wa[kk] = *(const float4*)&Ws[(k + kk) * F + f0];
                wb[kk] = *(const float4*)&Ws[(k + kk) * F + f0 + 4];
            }
#pragma unroll
            for (int i = 0; i < 8; i++) {
                float4 xv = *(const float4*)&Xs[(ngrp + 32 * i) * XP + k];
#pragma unroll
                for (int kk = 0; kk < 4; kk++) {
                    float xk = (kk == 0) ? xv.x : (kk == 1) ? xv.y : (kk == 2) ? xv.z : xv.w;
                    acc[i][0] = fmaf(xk, wa[kk].x, acc[i][0]);
                    acc[i][1] = fmaf(xk, wa[kk].y, acc[i][1]);
                    acc[i][2] = fmaf(xk, wa[kk].z, acc[i][2]);
                    acc[i][3] = fmaf(xk, wa[kk].w, acc[i][3]);
                    acc[i][4] = fmaf(xk, wb[kk].x, acc[i][4]);
                    acc[i][5] = fmaf(xk, wb[kk].y, acc[i][5]);
                    acc[i][6] = fmaf(xk, wb[kk].z, acc[i][6]);
                    acc[i][7] = fmaf(xk, wb[kk].w, acc[i][7]);
                }
            }
        }
    }
#pragma unroll
    for (int i = 0; i < 8; i++) {
        int gn = nb + ngrp + 32 * i;
        if (gn < N_NODES) {
            float di = dinv[gn];
            __hip_bfloat16 hb[8];
#pragma unroll
            for (int j = 0; j < 8; j++) hb[j] = __float2bfloat16(acc[i][j] * di);
            *(uint4*)&H[(size_t)gn * F + f0] = *(uint4*)hb;
        }
    }
}

// ---------------- aggregation: O = relu(b + dinv*(Hd_self + sum_in w*Hd[src])) ----------------
// EIGHT degree-matched nodes per wave: lane = (node_sub 3b, fgroup 3b). Each lane
// serially accumulates ALL edges of its node for its 8 features -> NO shuffle
// reduce; each lane stores its own 16 B of output. Exact-degree binning makes the
// 8 streams' trip counts equal (slot waste ~5%, only 4-edge window padding).
// 4 edges per window are issued back-to-back (4 gathers in flight, r1 pattern, no
// rotation movs). Out-of-range slots index the ZERO SENTINEL esec[N_EDGES]
// -> coef 0 + row-0 gather (L1-hot); fmaf(0,x,a)==a keeps sums exact.
#define ACC8(A, C, H)                                            \
    A[0] = fmaf(C, __uint_as_float((H).x << 16),         A[0]);  \
    A[1] = fmaf(C, __uint_as_float((H).x & 0xffff0000u), A[1]);  \
    A[2] = fmaf(C, __uint_as_float((H).y << 16),         A[2]);  \
    A[3] = fmaf(C, __uint_as_float((H).y & 0xffff0000u), A[3]);  \
    A[4] = fmaf(C, __uint_as_float((H).z << 16),         A[4]);  \
    A[5] = fmaf(C, __uint_as_float((H).z & 0xffff0000u), A[5]);  \
    A[6] = fmaf(C, __uint_as_float((H).w << 16),         A[6]);  \
    A[7] = fmaf(C, __uint_as_float((H).w & 0xffff0000u), A[7]);

__global__ __launch_bounds__(256) void k_agg(const __hip_bfloat16* __restrict__ Hd,
                                             const int* __restrict__ row_off,
                                             const int2* __restrict__ esec,
                                             const float* __restrict__ dinv,
                                             const float* __restrict__ bias,
                                             const int* __restrict__ perm,
                                             __hip_bfloat16* __restrict__ O) {
    int lane = threadIdx.x & 63;
    int wv   = threadIdx.x >> 6;
    int ns   = lane >> 3;               // node sub 0..7
    int f8   = lane & 7;                // feature group
    int np   = blockIdx.x * 32 + wv * 8 + ns;
    int node = perm[np];
    int r0 = row_off[node];
    int r1 = row_off[node + 1];
    int ml = r1 - r0;
    ml = max(ml, __shfl_xor(ml, 8));    // wave-uniform trip count (max over 8 nodes)
    ml = max(ml, __shfl_xor(ml, 16));
    ml = max(ml, __shfl_xor(ml, 32));
    const char* Hb = (const char*)Hd;
    const int fb = f8 << 4;

    float a[8];
#pragma unroll
    for (int u = 0; u < 8; u++) a[u] = 0.0f;

    int nw = (ml + 3) >> 2;
    int j = r0;
    for (int w = 0; w < nw; w++) {
        int2 e0 = esec[j     < r1 ? j     : N_EDGES];
        int2 e1 = esec[j + 1 < r1 ? j + 1 : N_EDGES];
        int2 e2 = esec[j + 2 < r1 ? j + 2 : N_EDGES];
        int2 e3 = esec[j + 3 < r1 ? j + 3 : N_EDGES];
        uint4 h0 = *(const uint4*)(Hb + (unsigned)e0.x + fb);
        uint4 h1 = *(const uint4*)(Hb + (unsigned)e1.x + fb);
        uint4 h2 = *(const uint4*)(Hb + (unsigned)e2.x + fb);
        uint4 h3 = *(const uint4*)(Hb + (unsigned)e3.x + fb);
        float c0 = __int_as_float(e0.y);
        float c1 = __int_as_float(e1.y);
        float c2 = __int_as_float(e2.y);
        float c3 = __int_as_float(e3.y);
        ACC8(a, c0, h0)
        ACC8(a, c1, h1)
        ACC8(a, c2, h2)
        ACC8(a, c3, h3)
        j += 4;
    }

    float di = dinv[node];
    uint4 hs = *(const uint4*)(Hb + (size_t)node * 128 + fb);
    float hv[8];
    hv[0] = __uint_as_float(hs.x << 16);
    hv[1] = __uint_as_float(hs.x & 0xffff0000u);
    hv[2] = __uint_as_float(hs.y << 16);
    hv[3] = __uint_as_float(hs.y & 0xffff0000u);
    hv[4] = __uint_as_float(hs.z << 16);
    hv[5] = __uint_as_float(hs.z & 0xffff0000u);
    hv[6] = __uint_as_float(hs.w << 16);
    hv[7] = __uint_as_float(hs.w & 0xffff0000u);
    const float4* bp = (const float4*)(bias + f8 * 8);
    float4 bv0 = bp[0], bv1 = bp[1];
    float r[8];
    // out = relu(b + di*(sum + Hd_self))   [Hd already carries dinv[src]]
    r[0] = fmaxf(fmaf(di, a[0] + hv[0], bv0.x), 0.0f);
    r[1] = fmaxf(fmaf(di, a[1] + hv[1], bv0.y), 0.0f);
    r[2] = fmaxf(fmaf(di, a[2] + hv[2], bv0.z), 0.0f);
    r[3] = fmaxf(fmaf(di, a[3] + hv[3], bv0.w), 0.0f);
    r[4] = fmaxf(fmaf(di, a[4] + hv[4], bv1.x), 0.0f);
    r[5] = fmaxf(fmaf(di, a[5] + hv[5], bv1.y), 0.0f);
    r[6] = fmaxf(fmaf(di, a[6] + hv[6], bv1.z), 0.0f);
    r[7] = fmaxf(fmaf(di, a[7] + hv[7], bv1.w), 0.0f);
    __hip_bfloat16 hb[8];
#pragma unroll
    for (int u = 0; u < 8; u++) hb[u] = __float2bfloat16(r[u]);
    *(uint4*)&O[(size_t)node * F + f8 * 8] = *(uint4*)hb;
}

// ---------------- fused mean-pool + final linear (bf16 input) ----------------
__global__ __launch_bounds__(512) void k_pool_linear(const __hip_bfloat16* __restrict__ H,
                                                     const int* __restrict__ gstart,
                                                     const float* __restrict__ Wl,
                                                     const float* __restrict__ bl,
                                                     float* __restrict__ out) {
    int g = blockIdx.x;
    int beg = gstart[g], end = gstart[g + 1];
    int lane = threadIdx.x & 63, wv = threadIdx.x >> 6;
    float acc = 0.0f;
    for (int r = beg + wv; r < end; r += 8)
        acc += __bfloat162float(H[(size_t)r * F + lane]);
    __shared__ float s[8][F];
    s[wv][lane] = acc;
    __syncthreads();
    if (wv == 0) {
        float tot = 0.0f;
#pragma unroll
        for (int w = 0; w < 8; w++) tot += s[w][lane];
        float cntf = (float)(end - beg);
        float p = tot / fmaxf(cntf, 1.0f);
        for (int c = 0; c < 10; c++) {
            float v = p * Wl[lane * 10 + c];
            for (int off = 32; off; off >>= 1) v += __shfl_down(v, off);
            if (lane == 0) out[g * 10 + c] = v + bl[c];
        }
    }
}

// ---------------- launch ----------------

extern "C" void kernel_launch(void* const* d_in, const int* in_sizes, int n_in,
                              void* d_out, int out_size, void* d_ws, size_t ws_size,
                              hipStream_t stream) {
    const float* x    = (const float*)d_in[0];
    const int*   ei   = (const int*)d_in[1];
    const float* ea   = (const float*)d_in[2];
    const int*   bat  = (const int*)d_in[3];
    const float* W1   = (const float*)d_in[4];
    const float* b1   = (const float*)d_in[5];
    const float* W2   = (const float*)d_in[6];
    const float* b2   = (const float*)d_in[7];
    const float* W3   = (const float*)d_in[8];
    const float* b3   = (const float*)d_in[9];
    const float* Wl   = (const float*)d_in[10];
    const float* bl   = (const float*)d_in[11];
    float* out = (float*)d_out;

    const int* src = ei;
    const int* dst = ei + N_EDGES;

    char* ws = (char*)d_ws;
    size_t off = 0;
    auto carve = [&](size_t bytes) {
        void* p = ws + off;
        off += (bytes + 255) & ~(size_t)255;
        return p;
    };
    float*          dinv    = (float*)carve(N_NODES * 4);
    int*            row_off = (int*)  carve((N_NODES + 1) * 4);
    int2*           esec    = (int2*) carve(((size_t)N_EDGES + 32) * 8);        // 12.8 MB
    __hip_bfloat16* hbuf    = (__hip_bfloat16*)carve((size_t)N_NODES * F * 2);  // 12.8 MB
    __hip_bfloat16* obuf    = (__hip_bfloat16*)carve((size_t)N_NODES * F * 2);  // 12.8 MB
    long long*      part    = (long long*)carve((size_t)N_EDGES * 8);           // 12.8 MB
    int*            hist    = (int*)  carve((size_t)NCHUNK * NBUCK * 4);        // 1.22 MB
    int*            btot    = (int*)  carve((NBUCK + 8) * 4);
    int*            base    = (int*)  carve((NBUCK + 8) * 4);
    int*            gstart  = (int*)  carve((N_GRAPHS + 1) * 4);
    int*            nhist   = (int*)  carve((size_t)NCHN * NBIN * 4);
    int*            perm    = (int*)  carve((size_t)N_NODES * 4);
    (void)ws_size; (void)in_sizes; (void)n_in; (void)out_size;

    k_hist        <<<NCHUNK, 1024, 0, stream>>>(dst, hist);
    k_colscan     <<<NBUCK,  512,  0, stream>>>(hist, btot);
    k_bscan_gstart<<<2,      512,  0, stream>>>(btot, base, bat, gstart);
    k_partition   <<<NCHUNK, 1024, 0, stream>>>(src, dst, ea, hist, base, part);
    k_degscat     <<<NBUCK,  512,  0, stream>>>(part, base, dinv, row_off, esec);
    k_nhist       <<<NCHN,   1024, 0, stream>>>(row_off, nhist);
    k_nscan       <<<1,      1024, 0, stream>>>(nhist);
    k_nscat       <<<NCHN,   1024, 0, stream>>>(row_off, nhist, perm);

    k_gemm1<<<GB, 256, 0, stream>>>(x, W1, dinv, hbuf);
    k_agg<<<N_NODES / 32, 256, 0, stream>>>(hbuf, row_off, esec, dinv, b1, perm, obuf);
    k_gemm<64><<<GB, 256, 0, stream>>>((const unsigned short*)obuf, W2, dinv, hbuf);
    k_agg<<<N_NODES / 32, 256, 0, stream>>>(hbuf, row_off, esec, dinv, b2, perm, obuf);
    k_gemm<64><<<GB, 256, 0, stream>>>((const unsigned short*)obuf, W3, dinv, hbuf);
    k_agg<<<N_NODES / 32, 256, 0, stream>>>(hbuf, row_off, esec, dinv, b3, perm, obuf);

    k_pool_linear<<<N_GRAPHS, 512, 0, stream>>>(obuf, gstart, Wl, bl, out);
}

// Round 7
// 359.884 us; speedup vs baseline: 1.0432x; 1.0432x over previous
//
#include <hip/hip_runtime.h>
#include <hip/hip_bf16.h>

#define N_NODES  100000
#define N_EDGES  1600000
#define N_GRAPHS 256
#define F 64
#define NBUCK  782    // ceil(N_NODES/128), bucket = dst >> 7
#define CHUNK  4096   // edges per partition chunk
#define NCHUNK 391    // ceil(1.6M/4096)
#define GB     391    // ceil(N_NODES/256) gemm blocks (256 nodes/block)

// ======== atomic-free CSR build: two-level counting sort ========

__global__ __launch_bounds__(1024) void k_hist(const int* __restrict__ dst, int* __restrict__ hist) {
    __shared__ int lh[NBUCK];
    int tid = threadIdx.x, chunk = blockIdx.x;
    for (int j = tid; j < NBUCK; j += 1024) lh[j] = 0;
    __syncthreads();
    int e0 = chunk * CHUNK;
#pragma unroll
    for (int i = 0; i < CHUNK / 1024; i++) {
        int e = e0 + i * 1024 + tid;
        if (e < N_EDGES) atomicAdd(&lh[dst[e] >> 7], 1);
    }
    __syncthreads();
    for (int j = tid; j < NBUCK; j += 1024) hist[chunk * NBUCK + j] = lh[j];
}

__global__ __launch_bounds__(512) void k_colscan(int* __restrict__ hist, int* __restrict__ btot) {
    __shared__ int ts[512];
    int b = blockIdx.x, tid = threadIdx.x;
    int v = (tid < NCHUNK) ? hist[tid * NBUCK + b] : 0;
    ts[tid] = v;
    __syncthreads();
    int x = v;
    for (int off = 1; off < 512; off <<= 1) {
        int t = (tid >= off) ? ts[tid - off] : 0;
        __syncthreads();
        x += t; ts[tid] = x;
        __syncthreads();
    }
    if (tid < NCHUNK) hist[tid * NBUCK + b] = x - v;
    if (tid == 511) btot[b] = x;
}

// block 0: scan bucket totals -> base; block 1: graph-boundary binary search
__global__ __launch_bounds__(512) void k_bscan_gstart(const int* __restrict__ btot, int* __restrict__ base,
                                                      const int* __restrict__ batch, int* __restrict__ gstart) {
    if (blockIdx.x == 1) {
        int g = threadIdx.x;
        if (g > N_GRAPHS) return;
        int lo = 0, hi = N_NODES;
        while (lo < hi) {
            int mid = (lo + hi) >> 1;
            if (batch[mid] < g) lo = mid + 1; else hi = mid;
        }
        gstart[g] = lo;
        return;
    }
    __shared__ int ts[256];
    int tid = threadIdx.x;
    int v[4], loc[4], run = 0;
    if (tid < 256) {
#pragma unroll
        for (int k = 0; k < 4; k++) {
            int c = tid * 4 + k;
            v[k] = (c < NBUCK) ? btot[c] : 0;
            loc[k] = run; run += v[k];
        }
        ts[tid] = run;
    }
    __syncthreads();
    int x = run;
    for (int off = 1; off < 256; off <<= 1) {
        int t = (tid >= off && tid < 256) ? ts[tid - off] : 0;
        __syncthreads();
        if (tid < 256) { x += t; ts[tid] = x; }
        __syncthreads();
    }
    if (tid < 256) {
        int texcl = x - run;
#pragma unroll
        for (int k = 0; k < 4; k++) {
            int c = tid * 4 + k;
            if (c < NBUCK) base[c] = texcl + loc[k];
        }
        if (tid == 255) base[NBUCK] = x;
    }
}

// edge partition (1024 threads, 3.1 KB LDS -> high occupancy)
__global__ __launch_bounds__(1024) void k_partition(const int* __restrict__ src, const int* __restrict__ dst,
                                                    const float* __restrict__ ew,
                                                    const int* __restrict__ hist, const int* __restrict__ base,
                                                    long long* __restrict__ part) {
    __shared__ int cursor[NBUCK];
    int tid = threadIdx.x, chunk = blockIdx.x;
    for (int j = tid; j < NBUCK; j += 1024) cursor[j] = base[j] + hist[chunk * NBUCK + j];
    __syncthreads();
    int e0 = chunk * CHUNK;
#pragma unroll
    for (int i = 0; i < CHUNK / 1024; i++) {
        int e = e0 + i * 1024 + tid;
        if (e < N_EDGES) {
            int d = dst[e];
            int pos = atomicAdd(&cursor[d >> 7], 1);
            unsigned lo = (unsigned)src[e] | ((unsigned)(d & 127) << 17);
            long long rec = (long long)((unsigned long long)lo |
                            ((unsigned long long)__float_as_uint(ew[e]) << 32));
            part[pos] = rec;
        }
    }
}

// ======== fused deg+scat (one launch; bucket's part slice stays L2-hot) ========
// Pass 1: degrees (LDS float atomics) -> dinv_g, counts -> row_off + LDS cursors.
// Pass 2: scatter esec = (src*128 byte-off, raw w bits). Coef is the PLAIN edge
// weight: dinv[src] is folded into the H buffer by the GEMM epilogue (Hd=dinv*H),
// dinv[dst] applied once in agg. No per-edge dinv gather. (r6-proven numerics.)
__global__ __launch_bounds__(512) void k_degscat(const long long* __restrict__ part,
                                                 const int* __restrict__ base,
                                                 float* __restrict__ dinv_g, int* __restrict__ row_off,
                                                 int2* __restrict__ esec) {
    __shared__ float fdeg[128];
    __shared__ int   cnt[128];
    __shared__ int   sc[128];
    __shared__ int   cursor[128];
    int b = blockIdx.x, tid = threadIdx.x;
    if (tid < 128) { fdeg[tid] = 1.0f; cnt[tid] = 0; }   // 1.0 = self-loop weight
    __syncthreads();
    int e0 = base[b], e1 = base[b + 1];
    for (int k = e0 + tid; k < e1; k += 512) {
        long long rec = part[k];
        int d7 = ((int)rec >> 17) & 127;
        atomicAdd(&fdeg[d7], __uint_as_float((unsigned)(rec >> 32)));
        atomicAdd(&cnt[d7], 1);
    }
    __syncthreads();
    int myc = 0, x = 0;
    if (tid < 128) {
        int node = b * 128 + tid;
        if (node < N_NODES) dinv_g[node] = rsqrtf(fdeg[tid]);
        myc = cnt[tid]; x = myc; sc[tid] = x;
    }
    __syncthreads();
    for (int off = 1; off < 128; off <<= 1) {
        int t = (tid < 128 && tid >= off) ? sc[tid - off] : 0;
        __syncthreads();
        if (tid < 128) { x += t; sc[tid] = x; }
        __syncthreads();
    }
    if (tid < 128) {
        int node = b * 128 + tid;
        int ro = e0 + (x - myc);
        if (node < N_NODES) row_off[node] = ro;
        cursor[tid] = ro;
    }
    if (b == 0 && tid == 0) row_off[N_NODES] = N_EDGES;
    __syncthreads();
    // pass 2: scatter (part slice is L2-hot from pass 1)
    for (int k = e0 + tid; k < e1; k += 512) {
        long long rec = part[k];
        int lo = (int)rec;
        int d7 = (lo >> 17) & 127;
        int s  = lo & 0x1FFFF;
        int pos = atomicAdd(&cursor[d7], 1);
        esec[pos] = make_int2(s << 7, (int)(unsigned)(rec >> 32));  // (byte off, raw w bits)
    }
    if (b == 0 && tid < 32) esec[N_EDGES + tid] = make_int2(0, 0);  // zero sentinels
}

// ---------------- GEMM1: Hd = dinv * (X_f32[N,128] @ W[128,64]), bf16 out ----------------
__global__ __launch_bounds__(256) void k_gemm1(const float* __restrict__ X,
                                               const float* __restrict__ W,
                                               const float* __restrict__ dinv,
                                               __hip_bfloat16* __restrict__ H) {
    constexpr int K = 128;
    constexpr int KC = 32;
    constexpr int XP = KC + 4;
    __shared__ float Xs[256 * XP];
    __shared__ float Ws[KC * F];
    const int tid  = threadIdx.x;
    const int fgrp = tid & 7;
    const int ngrp = tid >> 3;
    const int f0   = fgrp * 8;
    const int nb   = blockIdx.x * 256;

    float acc[8][8];
#pragma unroll
    for (int i = 0; i < 8; i++)
#pragma unroll
        for (int j = 0; j < 8; j++) acc[i][j] = 0.0f;

    for (int kc = 0; kc < K; kc += KC) {
        if (kc) __syncthreads();
#pragma unroll
        for (int pass = 0; pass < 8; pass++) {
            int idx = tid + pass * 256;
            int r = idx >> 3, q = idx & 7;
            int gr = nb + r; if (gr >= N_NODES) gr = N_NODES - 1;
            float4 v = *(const float4*)&X[(size_t)gr * K + kc + q * 4];
            *(float4*)&Xs[r * XP + q * 4] = v;
        }
#pragma unroll
        for (int pass = 0; pass < 2; pass++) {
            int idx = tid + pass * 256;
            float4 v = *(const float4*)&W[(size_t)(kc + (idx >> 4)) * F + (idx & 15) * 4];
            *(float4*)&Ws[idx * 4] = v;
        }
        __syncthreads();
#pragma unroll
        for (int k = 0; k < KC; k += 4) {
            float4 wa[4], wb[4];
#pragma unroll
            for (int kk = 0; kk < 4; kk++) {
                wa[kk] = *(const float4*)&Ws[(k + kk) * F + f0];
                wb[kk] = *(const float4*)&Ws[(k + kk) * F + f0 + 4];
            }
#pragma unroll
            for (int i = 0; i < 8; i++) {
                float4 xv = *(const float4*)&Xs[(ngrp + 32 * i) * XP + k];
#pragma unroll
                for (int kk = 0; kk < 4; kk++) {
                    float xk = (kk == 0) ? xv.x : (kk == 1) ? xv.y : (kk == 2) ? xv.z : xv.w;
                    acc[i][0] = fmaf(xk, wa[kk].x, acc[i][0]);
                    acc[i][1] = fmaf(xk, wa[kk].y, acc[i][1]);
                    acc[i][2] = fmaf(xk, wa[kk].z, acc[i][2]);
                    acc[i][3] = fmaf(xk, wa[kk].w, acc[i][3]);
                    acc[i][4] = fmaf(xk, wb[kk].x, acc[i][4]);
                    acc[i][5] = fmaf(xk, wb[kk].y, acc[i][5]);
                    acc[i][6] = fmaf(xk, wb[kk].z, acc[i][6]);
                    acc[i][7] = fmaf(xk, wb[kk].w, acc[i][7]);
                }
            }
        }
    }
#pragma unroll
    for (int i = 0; i < 8; i++) {
        int gn = nb + ngrp + 32 * i;
        if (gn < N_NODES) {
            float di = dinv[gn];
            __hip_bfloat16 hb[8];
#pragma unroll
            for (int j = 0; j < 8; j++) hb[j] = __float2bfloat16(acc[i][j] * di);
            *(uint4*)&H[(size_t)gn * F + f0] = *(uint4*)hb;
        }
    }
}

// ---------------- GEMM (layers 2/3): Hd = dinv * (X_bf16[N,64] @ W[64,64]), bf16 out ----------------
template <int K>
__global__ __launch_bounds__(256) void k_gemm(const unsigned short* __restrict__ X,
                                              const float* __restrict__ W,
                                              const float* __restrict__ dinv,
                                              __hip_bfloat16* __restrict__ H) {
    constexpr int KC = 32;
    constexpr int XP = KC + 4;
    __shared__ float Xs[256 * XP];
    __shared__ float Ws[KC * F];
    const int tid  = threadIdx.x;
    const int fgrp = tid & 7;
    const int ngrp = tid >> 3;
    const int f0   = fgrp * 8;
    const int nb   = blockIdx.x * 256;

    float acc[8][8];
#pragma unroll
    for (int i = 0; i < 8; i++)
#pragma unroll
        for (int j = 0; j < 8; j++) acc[i][j] = 0.0f;

    for (int kc = 0; kc < K; kc += KC) {
        if (kc) __syncthreads();
#pragma unroll
        for (int pass = 0; pass < 4; pass++) {
            int idx = tid + pass * 256;
            int r = idx >> 2, q = idx & 3;
            int gr = nb + r; if (gr >= N_NODES) gr = N_NODES - 1;
            uint4 v = *(const uint4*)&X[(size_t)gr * K + kc + q * 8];
            float* dp = &Xs[r * XP + q * 8];
            dp[0] = __uint_as_float(v.x << 16);
            dp[1] = __uint_as_float(v.x & 0xffff0000u);
            dp[2] = __uint_as_float(v.y << 16);
            dp[3] = __uint_as_float(v.y & 0xffff0000u);
            dp[4] = __uint_as_float(v.z << 16);
            dp[5] = __uint_as_float(v.z & 0xffff0000u);
            dp[6] = __uint_as_float(v.w << 16);
            dp[7] = __uint_as_float(v.w & 0xffff0000u);
        }
#pragma unroll
        for (int pass = 0; pass < 2; pass++) {
            int idx = tid + pass * 256;
            float4 v = *(const float4*)&W[(size_t)(kc + (idx >> 4)) * F + (idx & 15) * 4];
            *(float4*)&Ws[idx * 4] = v;
        }
        __syncthreads();
#pragma unroll
        for (int k = 0; k < KC; k += 4) {
            float4 wa[4], wb[4];
#pragma unroll
            for (int kk = 0; kk < 4; kk++) {
                wa[kk] = *(const float4*)&Ws[(k + kk) * F + f0];
                wb[kk] = *(const float4*)&Ws[(k + kk) * F + f0 + 4];
            }
#pragma unroll
            for (int i = 0; i < 8; i++) {
                float4 xv = *(const float4*)&Xs[(ngrp + 32 * i) * XP + k];
#pragma unroll
                for (int kk = 0; kk < 4; kk++) {
                    float xk = (kk == 0) ? xv.x : (kk == 1) ? xv.y : (kk == 2) ? xv.z : xv.w;
                    acc[i][0] = fmaf(xk, wa[kk].x, acc[i][0]);
                    acc[i][1] = fmaf(xk, wa[kk].y, acc[i][1]);
                    acc[i][2] = fmaf(xk, wa[kk].z, acc[i][2]);
                    acc[i][3] = fmaf(xk, wa[kk].w, acc[i][3]);
                    acc[i][4] = fmaf(xk, wb[kk].x, acc[i][4]);
                    acc[i][5] = fmaf(xk, wb[kk].y, acc[i][5]);
                    acc[i][6] = fmaf(xk, wb[kk].z, acc[i][6]);
                    acc[i][7] = fmaf(xk, wb[kk].w, acc[i][7]);
                }
            }
        }
    }
#pragma unroll
    for (int i = 0; i < 8; i++) {
        int gn = nb + ngrp + 32 * i;
        if (gn < N_NODES) {
            float di = dinv[gn];
            __hip_bfloat16 hb[8];
#pragma unroll
            for (int j = 0; j < 8; j++) hb[j] = __float2bfloat16(acc[i][j] * di);
            *(uint4*)&H[(size_t)gn * F + f0] = *(uint4*)hb;
        }
    }
}

// ---------------- aggregation: O = relu(b + dinv*(Hd_self + sum_in w*Hd[src])) ----------------
// r1-proven structure (best measured across 6 rounds): FOUR nodes per wave,
// 4 independent gather streams (8 loads in flight: 4 esec prefetch + 4 gathers),
// esec software-pipelined one window ahead, inactive slots clamp gather to row 0
// (L1-hot) with coef=0. Per-node FMA order unchanged -> exact sums.
__global__ __launch_bounds__(256) void k_agg(const __hip_bfloat16* __restrict__ Hd,
                                             const int* __restrict__ row_off,
                                             const int2* __restrict__ esec,
                                             const float* __restrict__ dinv,
                                             const float* __restrict__ bias,
                                             __hip_bfloat16* __restrict__ O) {
    int wv   = threadIdx.x >> 6;
    int lane = threadIdx.x & 63;
    int np   = blockIdx.x * 16 + wv * 4;
    int q  = lane >> 3;
    int f8 = lane & 7;
    int r0 = __builtin_amdgcn_readfirstlane(row_off[np]);
    int r1 = __builtin_amdgcn_readfirstlane(row_off[np + 1]);
    int r2 = __builtin_amdgcn_readfirstlane(row_off[np + 2]);
    int r3 = __builtin_amdgcn_readfirstlane(row_off[np + 3]);
    int r4 = __builtin_amdgcn_readfirstlane(row_off[np + 4]);
    const char* Hbase = (const char*)Hd;
    const int fb = f8 << 4;

    float a0[8], a1[8], a2[8], a3[8];
#pragma unroll
    for (int u = 0; u < 8; u++) { a0[u] = 0.0f; a1[u] = 0.0f; a2[u] = 0.0f; a3[u] = 0.0f; }

    int l0 = r1 - r0, l1 = r2 - r1, l2 = r3 - r2, l3 = r4 - r3;
    int ml = l0 > l1 ? l0 : l1;
    if (l2 > ml) ml = l2;
    if (l3 > ml) ml = l3;
    int iters = (ml + 7) >> 3;
    int j0 = r0 + q, j1 = r1 + q, j2 = r2 + q, j3 = r3 + q;

    // prologue: prefetch window 0's esec
    int2 ev0 = esec[j0 < N_EDGES ? j0 : N_EDGES];
    int2 ev1 = esec[j1 < N_EDGES ? j1 : N_EDGES];
    int2 ev2 = esec[j2 < N_EDGES ? j2 : N_EDGES];
    int2 ev3 = esec[j3 < N_EDGES ? j3 : N_EDGES];

    for (int it = 0; it < iters; it++) {
        int m0 = j0 + 8, m1 = j1 + 8, m2 = j2 + 8, m3 = j3 + 8;
        int2 en0 = esec[m0 < N_EDGES ? m0 : N_EDGES];   // prefetch next window
        int2 en1 = esec[m1 < N_EDGES ? m1 : N_EDGES];
        int2 en2 = esec[m2 < N_EDGES ? m2 : N_EDGES];
        int2 en3 = esec[m3 < N_EDGES ? m3 : N_EDGES];

        bool t0 = j0 < r1, t1 = j1 < r2, t2 = j2 < r3, t3 = j3 < r4;
        float c0 = t0 ? __int_as_float(ev0.y) : 0.0f;
        float c1 = t1 ? __int_as_float(ev1.y) : 0.0f;
        float c2 = t2 ? __int_as_float(ev2.y) : 0.0f;
        float c3 = t3 ? __int_as_float(ev3.y) : 0.0f;
        unsigned o0 = t0 ? (unsigned)ev0.x : 0u;        // inactive -> row 0 (L1-hot)
        unsigned o1 = t1 ? (unsigned)ev1.x : 0u;
        unsigned o2 = t2 ? (unsigned)ev2.x : 0u;
        unsigned o3 = t3 ? (unsigned)ev3.x : 0u;
        uint4 h0 = *(const uint4*)(Hbase + o0 + fb);
        uint4 h1 = *(const uint4*)(Hbase + o1 + fb);
        uint4 h2 = *(const uint4*)(Hbase + o2 + fb);
        uint4 h3 = *(const uint4*)(Hbase + o3 + fb);
        a0[0] = fmaf(c0, __uint_as_float(h0.x << 16),         a0[0]);
        a0[1] = fmaf(c0, __uint_as_float(h0.x & 0xffff0000u), a0[1]);
        a0[2] = fmaf(c0, __uint_as_float(h0.y << 16),         a0[2]);
        a0[3] = fmaf(c0, __uint_as_float(h0.y & 0xffff0000u), a0[3]);
        a0[4] = fmaf(c0, __uint_as_float(h0.z << 16),         a0[4]);
        a0[5] = fmaf(c0, __uint_as_float(h0.z & 0xffff0000u), a0[5]);
        a0[6] = fmaf(c0, __uint_as_float(h0.w << 16),         a0[6]);
        a0[7] = fmaf(c0, __uint_as_float(h0.w & 0xffff0000u), a0[7]);
        a1[0] = fmaf(c1, __uint_as_float(h1.x << 16),         a1[0]);
        a1[1] = fmaf(c1, __uint_as_float(h1.x & 0xffff0000u), a1[1]);
        a1[2] = fmaf(c1, __uint_as_float(h1.y << 16),         a1[2]);
        a1[3] = fmaf(c1, __uint_as_float(h1.y & 0xffff0000u), a1[3]);
        a1[4] = fmaf(c1, __uint_as_float(h1.z << 16),         a1[4]);
        a1[5] = fmaf(c1, __uint_as_float(h1.z & 0xffff0000u), a1[5]);
        a1[6] = fmaf(c1, __uint_as_float(h1.w << 16),         a1[6]);
        a1[7] = fmaf(c1, __uint_as_float(h1.w & 0xffff0000u), a1[7]);
        a2[0] = fmaf(c2, __uint_as_float(h2.x << 16),         a2[0]);
        a2[1] = fmaf(c2, __uint_as_float(h2.x & 0xffff0000u), a2[1]);
        a2[2] = fmaf(c2, __uint_as_float(h2.y << 16),         a2[2]);
        a2[3] = fmaf(c2, __uint_as_float(h2.y & 0xffff0000u), a2[3]);
        a2[4] = fmaf(c2, __uint_as_float(h2.z << 16),         a2[4]);
        a2[5] = fmaf(c2, __uint_as_float(h2.z & 0xffff0000u), a2[5]);
        a2[6] = fmaf(c2, __uint_as_float(h2.w << 16),         a2[6]);
        a2[7] = fmaf(c2, __uint_as_float(h2.w & 0xffff0000u), a2[7]);
        a3[0] = fmaf(c3, __uint_as_float(h3.x << 16),         a3[0]);
        a3[1] = fmaf(c3, __uint_as_float(h3.x & 0xffff0000u), a3[1]);
        a3[2] = fmaf(c3, __uint_as_float(h3.y << 16),         a3[2]);
        a3[3] = fmaf(c3, __uint_as_float(h3.y & 0xffff0000u), a3[3]);
        a3[4] = fmaf(c3, __uint_as_float(h3.z << 16),         a3[4]);
        a3[5] = fmaf(c3, __uint_as_float(h3.z & 0xffff0000u), a3[5]);
        a3[6] = fmaf(c3, __uint_as_float(h3.w << 16),         a3[6]);
        a3[7] = fmaf(c3, __uint_as_float(h3.w & 0xffff0000u), a3[7]);

        ev0 = en0; ev1 = en1; ev2 = en2; ev3 = en3;
        j0 = m0; j1 = m1; j2 = m2; j3 = m3;
    }
#pragma unroll
    for (int m = 8; m < 64; m <<= 1) {
#pragma unroll
        for (int u = 0; u < 8; u++) {
            a0[u] += __shfl_xor(a0[u], m);
            a1[u] += __shfl_xor(a1[u], m);
            a2[u] += __shfl_xor(a2[u], m);
            a3[u] += __shfl_xor(a3[u], m);
        }
    }
    if (q < 4) {
        int node = np + q;
        float av[8];
#pragma unroll
        for (int u = 0; u < 8; u++) {
            float t01 = (q & 1) ? a1[u] : a0[u];
            float t23 = (q & 1) ? a3[u] : a2[u];
            av[u] = (q & 2) ? t23 : t01;
        }
        float di = dinv[node];
        uint4 hs = *(const uint4*)(Hbase + (size_t)node * 128 + fb);
        float hv[8];
        hv[0] = __uint_as_float(hs.x << 16);
        hv[1] = __uint_as_float(hs.x & 0xffff0000u);
        hv[2] = __uint_as_float(hs.y << 16);
        hv[3] = __uint_as_float(hs.y & 0xffff0000u);
        hv[4] = __uint_as_float(hs.z << 16);
        hv[5] = __uint_as_float(hs.z & 0xffff0000u);
        hv[6] = __uint_as_float(hs.w << 16);
        hv[7] = __uint_as_float(hs.w & 0xffff0000u);
        const float4* bp = (const float4*)(bias + f8 * 8);
        float4 bv0 = bp[0], bv1 = bp[1];
        float r[8];
        // out = relu(b + di*(sum + Hd_self))   [Hd already carries dinv[src]]
        r[0] = fmaxf(fmaf(di, av[0] + hv[0], bv0.x), 0.0f);
        r[1] = fmaxf(fmaf(di, av[1] + hv[1], bv0.y), 0.0f);
        r[2] = fmaxf(fmaf(di, av[2] + hv[2], bv0.z), 0.0f);
        r[3] = fmaxf(fmaf(di, av[3] + hv[3], bv0.w), 0.0f);
        r[4] = fmaxf(fmaf(di, av[4] + hv[4], bv1.x), 0.0f);
        r[5] = fmaxf(fmaf(di, av[5] + hv[5], bv1.y), 0.0f);
        r[6] = fmaxf(fmaf(di, av[6] + hv[6], bv1.z), 0.0f);
        r[7] = fmaxf(fmaf(di, av[7] + hv[7], bv1.w), 0.0f);
        __hip_bfloat16 hb[8];
#pragma unroll
        for (int u = 0; u < 8; u++) hb[u] = __float2bfloat16(r[u]);
        *(uint4*)&O[(size_t)node * F + f8 * 8] = *(uint4*)hb;
    }
}

// ---------------- fused mean-pool + final linear (bf16 input) ----------------
__global__ __launch_bounds__(512) void k_pool_linear(const __hip_bfloat16* __restrict__ H,
                                                     const int* __restrict__ gstart,
                                                     const float* __restrict__ Wl,
                                                     const float* __restrict__ bl,
                                                     float* __restrict__ out) {
    int g = blockIdx.x;
    int beg = gstart[g], end = gstart[g + 1];
    int lane = threadIdx.x & 63, wv = threadIdx.x >> 6;
    float acc = 0.0f;
    for (int r = beg + wv; r < end; r += 8)
        acc += __bfloat162float(H[(size_t)r * F + lane]);
    __shared__ float s[8][F];
    s[wv][lane] = acc;
    __syncthreads();
    if (wv == 0) {
        float tot = 0.0f;
#pragma unroll
        for (int w = 0; w < 8; w++) tot += s[w][lane];
        float cntf = (float)(end - beg);
        float p = tot / fmaxf(cntf, 1.0f);
        for (int c = 0; c < 10; c++) {
            float v = p * Wl[lane * 10 + c];
            for (int off = 32; off; off >>= 1) v += __shfl_down(v, off);
            if (lane == 0) out[g * 10 + c] = v + bl[c];
        }
    }
}

// ---------------- launch ----------------

extern "C" void kernel_launch(void* const* d_in, const int* in_sizes, int n_in,
                              void* d_out, int out_size, void* d_ws, size_t ws_size,
                              hipStream_t stream) {
    const float* x    = (const float*)d_in[0];
    const int*   ei   = (const int*)d_in[1];
    const float* ea   = (const float*)d_in[2];
    const int*   bat  = (const int*)d_in[3];
    const float* W1   = (const float*)d_in[4];
    const float* b1   = (const float*)d_in[5];
    const float* W2   = (const float*)d_in[6];
    const float* b2   = (const float*)d_in[7];
    const float* W3   = (const float*)d_in[8];
    const float* b3   = (const float*)d_in[9];
    const float* Wl   = (const float*)d_in[10];
    const float* bl   = (const float*)d_in[11];
    float* out = (float*)d_out;

    const int* src = ei;
    const int* dst = ei + N_EDGES;

    char* ws = (char*)d_ws;
    size_t off = 0;
    auto carve = [&](size_t bytes) {
        void* p = ws + off;
        off += (bytes + 255) & ~(size_t)255;
        return p;
    };
    float*          dinv    = (float*)carve(N_NODES * 4);
    int*            row_off = (int*)  carve((N_NODES + 1) * 4);
    int2*           esec    = (int2*) carve(((size_t)N_EDGES + 32) * 8);        // 12.8 MB
    __hip_bfloat16* hbuf    = (__hip_bfloat16*)carve((size_t)N_NODES * F * 2);  // 12.8 MB
    __hip_bfloat16* obuf    = (__hip_bfloat16*)carve((size_t)N_NODES * F * 2);  // 12.8 MB
    long long*      part    = (long long*)carve((size_t)N_EDGES * 8);           // 12.8 MB
    int*            hist    = (int*)  carve((size_t)NCHUNK * NBUCK * 4);        // 1.22 MB
    int*            btot    = (int*)  carve((NBUCK + 8) * 4);
    int*            base    = (int*)  carve((NBUCK + 8) * 4);
    int*            gstart  = (int*)  carve((N_GRAPHS + 1) * 4);
    (void)ws_size; (void)in_sizes; (void)n_in; (void)out_size;

    k_hist        <<<NCHUNK, 1024, 0, stream>>>(dst, hist);
    k_colscan     <<<NBUCK,  512,  0, stream>>>(hist, btot);
    k_bscan_gstart<<<2,      512,  0, stream>>>(btot, base, bat, gstart);
    k_partition   <<<NCHUNK, 1024, 0, stream>>>(src, dst, ea, hist, base, part);
    k_degscat     <<<NBUCK,  512,  0, stream>>>(part, base, dinv, row_off, esec);

    k_gemm1<<<GB, 256, 0, stream>>>(x, W1, dinv, hbuf);
    k_agg<<<N_NODES / 16, 256, 0, stream>>>(hbuf, row_off, esec, dinv, b1, obuf);
    k_gemm<64><<<GB, 256, 0, stream>>>((const unsigned short*)obuf, W2, dinv, hbuf);
    k_agg<<<N_NODES / 16, 256, 0, stream>>>(hbuf, row_off, esec, dinv, b2, obuf);
    k_gemm<64><<<GB, 256, 0, stream>>>((const unsigned short*)obuf, W3, dinv, hbuf);
    k_agg<<<N_NODES / 16, 256, 0, stream>>>(hbuf, row_off, esec, dinv, b3, obuf);

    k_pool_linear<<<N_GRAPHS, 512, 0, stream>>>(obuf, gstart, Wl, bl, out);
}